// Round 11
// baseline (83.977 us; speedup 1.0000x reference)
//
#include <hip/hip_runtime.h>

// ReactionTerm v9: 8-row fp16 packing -> per-row LDS instruction cost halved.
// R9/R10 neutrality proved the kernel is LDS-instruction-rate bound (~107
// b128/thread), not schedule-bound. Same b128 ops now carry 8 rows as fp16
// instead of 4 rows as fp32. Products computed fp32 (rates stay fp32),
// rounded once to fp16 in the LDS buffer; accumulate fp32. Error ~3*2^-11
// per term, sums <= ~20 -> absmax ~0.05 vs threshold 0.2.
// LDS 80 KB (y_s 16 + buf 64) -> 2 blocks/CU; launch_bounds(1024,8) caps
// VGPR at 64. Geometry: B=4096, S=1024, N1=4096, N2=16384.

typedef __attribute__((ext_vector_type(8))) _Float16 half8;

#define SWL(k) ((k) ^ (((k) >> 3) & 7))

// ---------- setup: 10 blocks, one per 2048-term chunk (as R10) ---------------
// chunks 0..1 = first-order halves; chunks 2..9 = second-order eighths.
__global__ __launch_bounds__(1024) void setup_kernel(
    const int* __restrict__ i1p, const int* __restrict__ i2p,
    unsigned short* __restrict__ pos1, unsigned short* __restrict__ pos2,
    unsigned* __restrict__ segpack) {
    __shared__ int h[1024];
    __shared__ int c[1024];
    const int tid = threadIdx.x;
    const int ch  = blockIdx.x;
    const int* __restrict__ ip = (ch < 2) ? (i1p + ch * 2048)
                                          : (i2p + (ch - 2) * 2048);
    unsigned short* __restrict__ pos = (ch < 2) ? (pos1 + ch * 2048)
                                                : (pos2 + (ch - 2) * 2048);

    h[tid] = 0;
    __syncthreads();
    const int t0 = ip[2 * tid], t1 = ip[2 * tid + 1];
    atomicAdd(&h[t0], 1);
    atomicAdd(&h[t1], 1);
    __syncthreads();
    int n = h[tid];
    c[tid] = n;
    __syncthreads();
    for (int d = 1; d < 1024; d <<= 1) {
        int t = (tid >= d) ? c[tid - d] : 0;
        __syncthreads();
        if (tid >= d) c[tid] += t;
        __syncthreads();
    }
    int start = c[tid] - n;  // exclusive scan, < 2048
    segpack[ch * 1024 + tid] = (unsigned)start | ((unsigned)n << 16);
    __syncthreads();
    c[tid] = start;          // reuse as cursor
    __syncthreads();
    int p0 = atomicAdd(&c[t0], 1);
    int p1 = atomicAdd(&c[t1], 1);
    pos[2 * tid]     = (unsigned short)SWL(p0);   // swizzle baked in
    pos[2 * tid + 1] = (unsigned short)SWL(p1);
}

// ---------- main: 8 rows/block (fp16-packed), 1024 threads -------------------
__global__ __launch_bounds__(1024, 8) void reaction_gather8(
    const float* __restrict__ y_in, const float* __restrict__ rate_1,
    const float* __restrict__ rate_2,
    const int* __restrict__ i1r, const int* __restrict__ i2r,
    const unsigned short* __restrict__ pos1, const unsigned short* __restrict__ pos2,
    const unsigned* __restrict__ segpack,
    float* __restrict__ y_out) {
    __shared__ half8 y_s[1024];     // 16 KB: 8 rows packed fp16
    __shared__ half8 buf[2][2048];  // 64 KB: double-buffered product halves

    const int tid = threadIdx.x;
    const long b0 = (long)blockIdx.x * 8;
    const float* __restrict__ r1b = rate_1 + b0 * 4096;
    const float* __restrict__ r2b = rate_2 + b0 * 16384;

    float acc[8] = {0.f, 0.f, 0.f, 0.f, 0.f, 0.f, 0.f, 0.f};

#define LOAD_PH1(C)                                                            \
    int2     ia = ((const int2*)(i1r + (C) * 2048))[tid];                      \
    unsigned pp = ((const unsigned*)(pos1 + (C) * 2048))[tid];                 \
    float2 q[8];                                                               \
    _Pragma("unroll")                                                          \
    for (int r = 0; r < 8; ++r)                                                \
        q[r] = ((const float2*)(r1b + r * 4096 + (C) * 2048))[tid];

#define WRITE_PH1(P)                                                           \
    {                                                                          \
        half8 va = y_s[ia.x], vb = y_s[ia.y];                                  \
        half8 p0, p1;                                                          \
        _Pragma("unroll")                                                      \
        for (int r = 0; r < 8; ++r) {                                          \
            p0[r] = (_Float16)((float)va[r] * q[r].x);                         \
            p1[r] = (_Float16)((float)vb[r] * q[r].y);                         \
        }                                                                      \
        buf[P][pp & 0xffffu] = p0;                                             \
        buf[P][pp >> 16]     = p1;                                             \
    }

#define LOAD_PH2(C)                                                            \
    int4     e  = ((const int4*)(i2r + (C) * 4096))[tid];                      \
    unsigned pp = ((const unsigned*)(pos2 + (C) * 2048))[tid];                 \
    float2 q[8];                                                               \
    _Pragma("unroll")                                                          \
    for (int r = 0; r < 8; ++r)                                                \
        q[r] = ((const float2*)(r2b + r * 16384 + (C) * 2048))[tid];

#define WRITE_PH2(P)                                                           \
    {                                                                          \
        half8 a0 = y_s[e.x], c0 = y_s[e.y];                                    \
        half8 a1 = y_s[e.z], c1 = y_s[e.w];                                    \
        half8 p0, p1;                                                          \
        _Pragma("unroll")                                                      \
        for (int r = 0; r < 8; ++r) {                                          \
            p0[r] = (_Float16)((float)a0[r] * (float)c0[r] * q[r].x);          \
            p1[r] = (_Float16)((float)a1[r] * (float)c1[r] * q[r].y);          \
        }                                                                      \
        buf[P][pp & 0xffffu] = p0;                                             \
        buf[P][pp >> 16]     = p1;                                             \
    }

#define SUM(CH, P)                                                             \
    {                                                                          \
        unsigned sp = segpack[(CH) * 1024 + tid];                              \
        int s = (int)(sp & 0xffffu), n = (int)(sp >> 16);                      \
        for (int k = s; k < s + n; ++k) {                                      \
            half8 v = buf[P][SWL(k)];                                          \
            _Pragma("unroll")                                                  \
            for (int r = 0; r < 8; ++r) acc[r] += (float)v[r];                 \
        }                                                                      \
    }

#define B_ __syncthreads()

    // Prologue: issue chunk-0 loads, stage 8 y rows as fp16, write products 0.
    {
        LOAD_PH1(0)
        half8 hy;
#pragma unroll
        for (int r = 0; r < 8; ++r)
            hy[r] = (_Float16)y_in[(b0 + r) * 1024 + tid];
        y_s[tid] = hy;
        B_;  // y_s ready
        WRITE_PH1(0)
    }
    B_;
    { LOAD_PH1(1) SUM(0, 0) WRITE_PH1(1) }  B_;
    { LOAD_PH2(0) SUM(1, 1) WRITE_PH2(0) }  B_;
    { LOAD_PH2(1) SUM(2, 0) WRITE_PH2(1) }  B_;
    { LOAD_PH2(2) SUM(3, 1) WRITE_PH2(0) }  B_;
    { LOAD_PH2(3) SUM(4, 0) WRITE_PH2(1) }  B_;
    { LOAD_PH2(4) SUM(5, 1) WRITE_PH2(0) }  B_;
    { LOAD_PH2(5) SUM(6, 0) WRITE_PH2(1) }  B_;
    { LOAD_PH2(6) SUM(7, 1) WRITE_PH2(0) }  B_;
    { LOAD_PH2(7) SUM(8, 0) WRITE_PH2(1) }  B_;
    SUM(9, 1)

#pragma unroll
    for (int r = 0; r < 8; ++r)
        y_out[(b0 + r) * 1024 + tid] = acc[r];

#undef LOAD_PH1
#undef WRITE_PH1
#undef LOAD_PH2
#undef WRITE_PH2
#undef SUM
#undef B_
}

// ---------- Fallback (generic sizes) ------------------------------------------
template <int BLOCK>
__global__ __launch_bounds__(BLOCK) void reaction_fallback(
    const float* __restrict__ y_in, const float* __restrict__ rate_1,
    const float* __restrict__ rate_2, const int* __restrict__ inds_1r,
    const int* __restrict__ inds_1p, const int* __restrict__ inds_2r,
    const int* __restrict__ inds_2p, float* __restrict__ y_out,
    int S, int N1, int N2) {
    extern __shared__ float smem[];
    float* y_s = smem;
    float* acc = smem + S;
    const int b = blockIdx.x, tid = threadIdx.x;
    const float* yrow = y_in + (size_t)b * S;
    for (int i = tid; i < S; i += BLOCK) { y_s[i] = yrow[i]; acc[i] = 0.f; }
    __syncthreads();
    const float* r1 = rate_1 + (size_t)b * N1;
    for (int i = tid; i < N1; i += BLOCK)
        atomicAdd(&acc[inds_1p[i]], y_s[inds_1r[i]] * r1[i]);
    const float* r2 = rate_2 + (size_t)b * N2;
    for (int i = tid; i < N2; i += BLOCK)
        atomicAdd(&acc[inds_2p[i]], y_s[inds_2r[2 * i]] * y_s[inds_2r[2 * i + 1]] * r2[i]);
    __syncthreads();
    float* orow = y_out + (size_t)b * S;
    for (int i = tid; i < S; i += BLOCK) orow[i] = acc[i];
}

extern "C" void kernel_launch(void* const* d_in, const int* in_sizes, int n_in,
                              void* d_out, int out_size, void* d_ws, size_t ws_size,
                              hipStream_t stream) {
    const float* y_in    = (const float*)d_in[0];
    const float* rate_1  = (const float*)d_in[1];
    const float* rate_2  = (const float*)d_in[2];
    const int*   inds_1r = (const int*)d_in[3];
    const int*   inds_1p = (const int*)d_in[4];
    const int*   inds_2r = (const int*)d_in[5];
    const int*   inds_2p = (const int*)d_in[6];
    float*       y_out   = (float*)d_out;

    const int N1 = in_sizes[3];           // 4096
    const int N2 = in_sizes[6];           // 16384
    const int B  = in_sizes[1] / N1;      // 4096
    const int S  = in_sizes[0] / B;       // 1024

    const bool specialized = (S == 1024 && N1 == 4096 && N2 == 16384 &&
                              (B % 8) == 0 && ws_size >= (size_t)(80 * 1024));
    if (!specialized) {
        size_t smem = (size_t)2 * S * sizeof(float);
        reaction_fallback<256><<<B, 256, smem, stream>>>(
            y_in, rate_1, rate_2, inds_1r, inds_1p, inds_2r, inds_2p,
            y_out, S, N1, N2);
        return;
    }

    // Workspace:
    //   segpack : 10240 u32 [ 0K, 40K)  (10 chunks; start | n<<16)
    //   pos1    :  4096 u16 [40K, 48K)  (chunk-local swizzled positions)
    //   pos2    : 16384 u16 [48K, 80K)
    char* ws = (char*)d_ws;
    unsigned*       segpack = (unsigned*)(ws + 0);
    unsigned short* pos1    = (unsigned short*)(ws + 40 * 1024);
    unsigned short* pos2    = (unsigned short*)(ws + 48 * 1024);

    setup_kernel<<<10, 1024, 0, stream>>>(inds_1p, inds_2p, pos1, pos2, segpack);
    reaction_gather8<<<B / 8, 1024, 0, stream>>>(y_in, rate_1, rate_2,
                                                 inds_1r, inds_2r, pos1, pos2,
                                                 segpack, y_out);
}

// Round 12
// 79.420 us; speedup vs baseline: 1.0574x; 1.0574x over previous
//
#include <hip/hip_runtime.h>

// ReactionTerm v10: float4 rate loads + fp16 double-buffer + fast setup.
// R9/R10/R11 nulls proved: not schedule-bound, not LDS-instr bound. Residual
// vs 52us HBM floor = read efficiency + setup serialization + tail skew.
// R12: 4096-term chunks (5 total) so rate loads are float4 (16B/lane, 4
// streams); buf is fp16 half4 (error validated in R11: absmax 0.0625 << 0.2)
// so double-buffering fits: 8KB y_s + 64KB buf = 72KB -> 2 blocks/CU.
// Setup scan via __shfl_up butterfly (5 barriers, was 23). 1024 blocks ->
// 2 residency rounds. Geometry: B=4096, S=1024, N1=4096, N2=16384.

typedef __attribute__((ext_vector_type(4))) _Float16 half4;

#define SWL(k) ((k) ^ (((k) >> 3) & 7))

// ---------- setup: 5 blocks (0: ph1; 1..4: ph2 chunk), 4096 terms each -------
__global__ __launch_bounds__(1024) void setup_kernel(
    const int* __restrict__ i1p, const int* __restrict__ i2p,
    unsigned short* __restrict__ pos1, unsigned short* __restrict__ pos2,
    unsigned* __restrict__ segpack) {
    __shared__ int h[1024];
    __shared__ int wsum[16];
    const int tid = threadIdx.x;
    const int ch  = blockIdx.x;
    const int* __restrict__ ip = (ch == 0) ? i1p : (i2p + (ch - 1) * 4096);
    unsigned short* __restrict__ pos = (ch == 0) ? pos1 : (pos2 + (ch - 1) * 4096);

    h[tid] = 0;
    __syncthreads();
    const int4 t4 = ((const int4*)ip)[tid];   // terms 4tid..4tid+3
    atomicAdd(&h[t4.x], 1);
    atomicAdd(&h[t4.y], 1);
    atomicAdd(&h[t4.z], 1);
    atomicAdd(&h[t4.w], 1);
    __syncthreads();
    const int n = h[tid];

    // 1024-wide exclusive scan: wave shfl butterfly + 16-wave combine.
    const int lane = tid & 63, w = tid >> 6;
    int v = n;
#pragma unroll
    for (int d = 1; d < 64; d <<= 1) {
        int t = __shfl_up(v, d, 64);
        if (lane >= d) v += t;
    }
    if (lane == 63) wsum[w] = v;
    __syncthreads();
    if (tid < 16) {
        int s = wsum[tid];
#pragma unroll
        for (int d = 1; d < 16; d <<= 1) {
            int t = __shfl_up(s, d, 64);
            if (tid >= d) s += t;
        }
        wsum[tid] = s;
    }
    __syncthreads();
    const int start = ((w ? wsum[w - 1] : 0) + v) - n;   // exclusive
    segpack[ch * 1024 + tid] = (unsigned)start | ((unsigned)n << 16);
    __syncthreads();
    h[tid] = start;                                      // reuse as cursor
    __syncthreads();
    const int p0 = atomicAdd(&h[t4.x], 1);
    const int p1 = atomicAdd(&h[t4.y], 1);
    const int p2 = atomicAdd(&h[t4.z], 1);
    const int p3 = atomicAdd(&h[t4.w], 1);
    ushort4 o;
    o.x = (unsigned short)SWL(p0);
    o.y = (unsigned short)SWL(p1);
    o.z = (unsigned short)SWL(p2);
    o.w = (unsigned short)SWL(p3);
    ((ushort4*)pos)[tid] = o;
}

// ---------- main: 4 rows/block (fp16 buf), 1024 threads ----------------------
__global__ __launch_bounds__(1024, 8) void reaction_gather4h(
    const float* __restrict__ y_in, const float* __restrict__ rate_1,
    const float* __restrict__ rate_2,
    const int* __restrict__ i1r, const int* __restrict__ i2r,
    const unsigned short* __restrict__ pos1, const unsigned short* __restrict__ pos2,
    const unsigned* __restrict__ segpack,
    float* __restrict__ y_out) {
    __shared__ half4 y_s[1024];     //  8 KB: 4 rows fp16
    __shared__ half4 buf[2][4096];  // 64 KB: double-buffered product chunks

    const int tid = threadIdx.x;
    const long b0 = (long)blockIdx.x * 4;
    const float* __restrict__ r1b = rate_1 + b0 * 4096;
    const float* __restrict__ r2b = rate_2 + b0 * 16384;

    float acc[4] = {0.f, 0.f, 0.f, 0.f};

    // q0..q3 = row r's rates for this thread's 4 terms (float4, 16B/lane).
#define LOAD_PH1()                                                             \
    int4    ia = ((const int4*)i1r)[tid];                                      \
    ushort4 pp = ((const ushort4*)pos1)[tid];                                  \
    float4 q0 = ((const float4*)(r1b         ))[tid];                          \
    float4 q1 = ((const float4*)(r1b +  4096))[tid];                           \
    float4 q2 = ((const float4*)(r1b +  8192))[tid];                           \
    float4 q3 = ((const float4*)(r1b + 12288))[tid];

#define WRITE_PH1(P)                                                           \
    {                                                                          \
        half4 yv, pr;                                                          \
        yv = y_s[ia.x];                                                        \
        pr[0] = (_Float16)((float)yv[0] * q0.x); pr[1] = (_Float16)((float)yv[1] * q1.x); \
        pr[2] = (_Float16)((float)yv[2] * q2.x); pr[3] = (_Float16)((float)yv[3] * q3.x); \
        buf[P][pp.x] = pr;                                                     \
        yv = y_s[ia.y];                                                        \
        pr[0] = (_Float16)((float)yv[0] * q0.y); pr[1] = (_Float16)((float)yv[1] * q1.y); \
        pr[2] = (_Float16)((float)yv[2] * q2.y); pr[3] = (_Float16)((float)yv[3] * q3.y); \
        buf[P][pp.y] = pr;                                                     \
        yv = y_s[ia.z];                                                        \
        pr[0] = (_Float16)((float)yv[0] * q0.z); pr[1] = (_Float16)((float)yv[1] * q1.z); \
        pr[2] = (_Float16)((float)yv[2] * q2.z); pr[3] = (_Float16)((float)yv[3] * q3.z); \
        buf[P][pp.z] = pr;                                                     \
        yv = y_s[ia.w];                                                        \
        pr[0] = (_Float16)((float)yv[0] * q0.w); pr[1] = (_Float16)((float)yv[1] * q1.w); \
        pr[2] = (_Float16)((float)yv[2] * q2.w); pr[3] = (_Float16)((float)yv[3] * q3.w); \
        buf[P][pp.w] = pr;                                                     \
    }

#define LOAD_PH2(C)                                                            \
    int4    e0 = ((const int4*)(i2r + (C) * 8192))[2 * tid];      /* t0,t1 */  \
    int4    e1 = ((const int4*)(i2r + (C) * 8192))[2 * tid + 1];  /* t2,t3 */  \
    ushort4 pp = ((const ushort4*)(pos2 + (C) * 4096))[tid];                   \
    float4 q0 = ((const float4*)(r2b + (C) * 4096         ))[tid];             \
    float4 q1 = ((const float4*)(r2b + (C) * 4096 + 16384))[tid];              \
    float4 q2 = ((const float4*)(r2b + (C) * 4096 + 32768))[tid];              \
    float4 q3 = ((const float4*)(r2b + (C) * 4096 + 49152))[tid];

#define WRITE_PH2(P)                                                           \
    {                                                                          \
        half4 ya, yb, pr;                                                      \
        ya = y_s[e0.x]; yb = y_s[e0.y];                                        \
        pr[0] = (_Float16)((float)ya[0] * (float)yb[0] * q0.x);                \
        pr[1] = (_Float16)((float)ya[1] * (float)yb[1] * q1.x);                \
        pr[2] = (_Float16)((float)ya[2] * (float)yb[2] * q2.x);                \
        pr[3] = (_Float16)((float)ya[3] * (float)yb[3] * q3.x);                \
        buf[P][pp.x] = pr;                                                     \
        ya = y_s[e0.z]; yb = y_s[e0.w];                                        \
        pr[0] = (_Float16)((float)ya[0] * (float)yb[0] * q0.y);                \
        pr[1] = (_Float16)((float)ya[1] * (float)yb[1] * q1.y);                \
        pr[2] = (_Float16)((float)ya[2] * (float)yb[2] * q2.y);                \
        pr[3] = (_Float16)((float)ya[3] * (float)yb[3] * q3.y);                \
        buf[P][pp.y] = pr;                                                     \
        ya = y_s[e1.x]; yb = y_s[e1.y];                                        \
        pr[0] = (_Float16)((float)ya[0] * (float)yb[0] * q0.z);                \
        pr[1] = (_Float16)((float)ya[1] * (float)yb[1] * q1.z);                \
        pr[2] = (_Float16)((float)ya[2] * (float)yb[2] * q2.z);                \
        pr[3] = (_Float16)((float)ya[3] * (float)yb[3] * q3.z);                \
        buf[P][pp.z] = pr;                                                     \
        ya = y_s[e1.z]; yb = y_s[e1.w];                                        \
        pr[0] = (_Float16)((float)ya[0] * (float)yb[0] * q0.w);                \
        pr[1] = (_Float16)((float)ya[1] * (float)yb[1] * q1.w);                \
        pr[2] = (_Float16)((float)ya[2] * (float)yb[2] * q2.w);                \
        pr[3] = (_Float16)((float)ya[3] * (float)yb[3] * q3.w);                \
        buf[P][pp.w] = pr;                                                     \
    }

#define SUM(CH, P)                                                             \
    {                                                                          \
        unsigned sp = segpack[(CH) * 1024 + tid];                              \
        int s = (int)(sp & 0xffffu), n = (int)(sp >> 16);                      \
        for (int k = s; k < s + n; ++k) {                                      \
            half4 v = buf[P][SWL(k)];                                          \
            acc[0] += (float)v[0]; acc[1] += (float)v[1];                      \
            acc[2] += (float)v[2]; acc[3] += (float)v[3];                      \
        }                                                                      \
    }

#define B_ __syncthreads()

    // Prologue: issue ph1 loads, stage y rows (fp16), write products 0.
    {
        LOAD_PH1()
        half4 hy;
#pragma unroll
        for (int r = 0; r < 4; ++r)
            hy[r] = (_Float16)y_in[(b0 + r) * 1024 + tid];
        y_s[tid] = hy;
        B_;  // y_s ready
        WRITE_PH1(0)
    }
    B_;
    { LOAD_PH2(0) SUM(0, 0) WRITE_PH2(1) }  B_;
    { LOAD_PH2(1) SUM(1, 1) WRITE_PH2(0) }  B_;
    { LOAD_PH2(2) SUM(2, 0) WRITE_PH2(1) }  B_;
    { LOAD_PH2(3) SUM(3, 1) WRITE_PH2(0) }  B_;
    SUM(4, 0)

#pragma unroll
    for (int r = 0; r < 4; ++r)
        y_out[(b0 + r) * 1024 + tid] = acc[r];

#undef LOAD_PH1
#undef WRITE_PH1
#undef LOAD_PH2
#undef WRITE_PH2
#undef SUM
#undef B_
}

// ---------- Fallback (generic sizes) ------------------------------------------
template <int BLOCK>
__global__ __launch_bounds__(BLOCK) void reaction_fallback(
    const float* __restrict__ y_in, const float* __restrict__ rate_1,
    const float* __restrict__ rate_2, const int* __restrict__ inds_1r,
    const int* __restrict__ inds_1p, const int* __restrict__ inds_2r,
    const int* __restrict__ inds_2p, float* __restrict__ y_out,
    int S, int N1, int N2) {
    extern __shared__ float smem[];
    float* y_s = smem;
    float* acc = smem + S;
    const int b = blockIdx.x, tid = threadIdx.x;
    const float* yrow = y_in + (size_t)b * S;
    for (int i = tid; i < S; i += BLOCK) { y_s[i] = yrow[i]; acc[i] = 0.f; }
    __syncthreads();
    const float* r1 = rate_1 + (size_t)b * N1;
    for (int i = tid; i < N1; i += BLOCK)
        atomicAdd(&acc[inds_1p[i]], y_s[inds_1r[i]] * r1[i]);
    const float* r2 = rate_2 + (size_t)b * N2;
    for (int i = tid; i < N2; i += BLOCK)
        atomicAdd(&acc[inds_2p[i]], y_s[inds_2r[2 * i]] * y_s[inds_2r[2 * i + 1]] * r2[i]);
    __syncthreads();
    float* orow = y_out + (size_t)b * S;
    for (int i = tid; i < S; i += BLOCK) orow[i] = acc[i];
}

extern "C" void kernel_launch(void* const* d_in, const int* in_sizes, int n_in,
                              void* d_out, int out_size, void* d_ws, size_t ws_size,
                              hipStream_t stream) {
    const float* y_in    = (const float*)d_in[0];
    const float* rate_1  = (const float*)d_in[1];
    const float* rate_2  = (const float*)d_in[2];
    const int*   inds_1r = (const int*)d_in[3];
    const int*   inds_1p = (const int*)d_in[4];
    const int*   inds_2r = (const int*)d_in[5];
    const int*   inds_2p = (const int*)d_in[6];
    float*       y_out   = (float*)d_out;

    const int N1 = in_sizes[3];           // 4096
    const int N2 = in_sizes[6];           // 16384
    const int B  = in_sizes[1] / N1;      // 4096
    const int S  = in_sizes[0] / B;       // 1024

    const bool specialized = (S == 1024 && N1 == 4096 && N2 == 16384 &&
                              (B % 4) == 0 && ws_size >= (size_t)(60 * 1024));
    if (!specialized) {
        size_t smem = (size_t)2 * S * sizeof(float);
        reaction_fallback<256><<<B, 256, smem, stream>>>(
            y_in, rate_1, rate_2, inds_1r, inds_1p, inds_2r, inds_2p,
            y_out, S, N1, N2);
        return;
    }

    // Workspace:
    //   segpack : 5120 u32  [ 0K, 20K)  (ph1 + 4 ph2 chunks; start | n<<16)
    //   pos1    : 4096 u16  [20K, 28K)  (swizzled positions)
    //   pos2    : 16384 u16 [28K, 60K)  (chunk-local swizzled positions)
    char* ws = (char*)d_ws;
    unsigned*       segpack = (unsigned*)(ws + 0);
    unsigned short* pos1    = (unsigned short*)(ws + 20 * 1024);
    unsigned short* pos2    = (unsigned short*)(ws + 28 * 1024);

    setup_kernel<<<5, 1024, 0, stream>>>(inds_1p, inds_2p, pos1, pos2, segpack);
    reaction_gather4h<<<B / 4, 1024, 0, stream>>>(y_in, rate_1, rate_2,
                                                  inds_1r, inds_2r, pos1, pos2,
                                                  segpack, y_out);
}